// Round 11
// baseline (317.111 us; speedup 1.0000x reference)
//
#include <hip/hip_runtime.h>

// Problem constants (from setup_inputs): B=16, C=320, H=W=64, G=5, Cg=64
#define BATCH 16
#define CHAN  320
#define HH    64
#define WW    64
#define PLANE (HH*WW)            // 4096
#define NGRP  5
#define CG    64                 // CHAN / NGRP

// Static device scratch (module-load allocated; avoids any dependence on
// ws_size). Fully overwritten before being read on every kernel_launch call.
__device__ float g_em[BATCH * PLANE];   // channel SUM of edge_guidance
__device__ float g_w0[BATCH * PLANE];   // softmax weight for the H-shift term

// ---------------------------------------------------------------------------
// Kernel 1: g_em[b,r,q] = sum_c edge_guidance[b,c,r,q]
// ---------------------------------------------------------------------------
__global__ void k_reduce_mean(const float* __restrict__ eg)
{
    __shared__ float red[256];
    const int bid = blockIdx.x;           // b*64 + r
    const int b = bid >> 6;
    const int r = bid & 63;
    const int q   = threadIdx.x & 63;
    const int grp = threadIdx.x >> 6;     // 0..3, each owns 80 channels

    const float* p = eg + (((size_t)b * CHAN + (size_t)grp * 80) * PLANE) + r * WW + q;
    float s = 0.f;
#pragma unroll 8
    for (int c = 0; c < 80; ++c)
        s += p[(size_t)c * PLANE];

    red[threadIdx.x] = s;
    __syncthreads();
    if (grp == 0) {
        g_em[(size_t)bid * 64 + q] = red[q] + red[q + 64] + red[q + 128] + red[q + 192];
    }
}

// ---------------------------------------------------------------------------
// Kernel 2: fused conv1+relu -> conv2 -> softmax -> w0
// ---------------------------------------------------------------------------
__global__ void k_conv_dir(const float* __restrict__ w1, const float* __restrict__ b1,
                           const float* __restrict__ w2, const float* __restrict__ b2)
{
    __shared__ float sem[20][20];
    __shared__ float shh[18][18];
    __shared__ float sw1[16][9];
    __shared__ float sb1[16];
    __shared__ float sw2[2][16][9];
    __shared__ float sb2[2];

    const int bid = blockIdx.x;
    const int b  = bid >> 4;
    const int t  = bid & 15;
    const int r0 = (t >> 2) * 16;
    const int q0 = (t & 3) * 16;
    const int tid = threadIdx.x;

    if (tid < 144) sw1[tid / 9][tid % 9] = w1[tid];
    if (tid < 16)  sb1[tid] = b1[tid];
    for (int i = tid; i < 288; i += 256) ((float*)sw2)[i] = w2[i];
    if (tid < 2)   sb2[tid] = b2[tid];

    const float scale = 1.0f / (float)CHAN;
    for (int i = tid; i < 400; i += 256) {
        const int lr = i / 20, lq = i % 20;
        const int r = r0 + lr - 2, q = q0 + lq - 2;
        float v = 0.f;
        if ((unsigned)r < HH && (unsigned)q < WW)
            v = g_em[((size_t)b * HH + r) * WW + q] * scale;
        sem[lr][lq] = v;
    }
    __syncthreads();

    const int lr = tid >> 4;
    const int lq = tid & 15;
    float l0 = sb2[0];
    float l1 = sb2[1];

    for (int i = 0; i < 16; ++i) {
        for (int p = tid; p < 324; p += 256) {
            const int hr = p / 18, hq = p % 18;
            const int gr = r0 - 1 + hr, gq = q0 - 1 + hq;
            float acc = 0.f;
            if ((unsigned)gr < HH && (unsigned)gq < WW) {
                acc = sb1[i];
#pragma unroll
                for (int dr = 0; dr < 3; ++dr)
#pragma unroll
                    for (int dq = 0; dq < 3; ++dq)
                        acc += sem[hr + dr][hq + dq] * sw1[i][dr * 3 + dq];
                acc = fmaxf(acc, 0.f);
            }
            shh[hr][hq] = acc;
        }
        __syncthreads();
#pragma unroll
        for (int dr = 0; dr < 3; ++dr)
#pragma unroll
            for (int dq = 0; dq < 3; ++dq) {
                const float hv = shh[lr + dr][lq + dq];
                l0 += hv * sw2[0][i][dr * 3 + dq];
                l1 += hv * sw2[1][i][dr * 3 + dq];
            }
        __syncthreads();
    }

    const float m  = fmaxf(l0, l1);
    const float e0 = expf(l0 - m);
    const float e1 = expf(l1 - m);
    const float w0v = e0 / (e0 + e1);
    g_w0[((size_t)b * HH + (r0 + lr)) * WW + (q0 + lq)] = w0v;
}

// ---------------------------------------------------------------------------
// Kernel 3 (production, unchanged from round 10 — passing, ~51us)
// ---------------------------------------------------------------------------
template <int SW>
__device__ __forceinline__ void sb_loop(const float* __restrict__ pb,
                                        float* __restrict__ ob,
                                        int base, int moff, int hoff,
                                        float hm, float m0, float m1,
                                        float m2, float m3, const float4 wv)
{
#pragma unroll
    for (int i = 0; i < 16; ++i) {
        const float4 xv = *(const float4*)(pb + base);
        float4 xm = make_float4(0.f, 0.f, 0.f, 0.f);
        if constexpr (SW != 0) xm = *(const float4*)(pb + moff);
        const float4 xh = *(const float4*)(pb + hoff);

        float xw0, xw1, xw2, xw3;
        if constexpr (SW == 0)      { xw0 = xv.x; xw1 = xv.y; xw2 = xv.z; xw3 = xv.w; }
        else if constexpr (SW == 1) { xw0 = xm.w; xw1 = xv.x; xw2 = xv.y; xw3 = xv.z; }
        else if constexpr (SW == 2) { xw0 = xm.z; xw1 = xm.w; xw2 = xv.x; xw3 = xv.y; }
        else if constexpr (SW == -1){ xw0 = xv.y; xw1 = xv.z; xw2 = xv.w; xw3 = xm.x; }
        else                        { xw0 = xv.z; xw1 = xv.w; xw2 = xm.x; xw3 = xm.y; }
        xw0 *= m0; xw1 *= m1; xw2 *= m2; xw3 *= m3;

        float4 o;
        o.x = xw0 + wv.x * (hm * xh.x - xw0);
        o.y = xw1 + wv.y * (hm * xh.y - xw1);
        o.z = xw2 + wv.z * (hm * xh.z - xw2);
        o.w = xw3 + wv.w * (hm * xh.w - xw3);
        *(float4*)(ob + base) = o;

        pb += PLANE; ob += PLANE;
    }
}

__global__ __launch_bounds__(256) void k_shift_blend(
        const float* __restrict__ x,
        const int* __restrict__ sh_arr, const int* __restrict__ sw_arr,
        float* __restrict__ out)
{
    const int tid  = threadIdx.x;
    const int lane = tid & 63;
    const int csub = tid >> 6;

    const int bid = blockIdx.x;            // b*(NGRP*16) + g*16 + s
    const int s   = bid & 15;
    const int g   = (bid >> 4) % NGRP;
    const int b   = bid / (NGRP * 16);
    const int sh  = sh_arr[g];
    const int sw  = sw_arr[g];

    const int p4  = s * 64 + lane;
    const int r   = p4 >> 4;
    const int q   = (p4 & 15) * 4;
    const int base = r * WW + q;

    const int rs  = r - sh;
    const float hm = ((unsigned)rs < HH) ? 1.f : 0.f;
    const int rsc = rs < 0 ? 0 : (rs > HH - 1 ? HH - 1 : rs);
    const int hoff = rsc * WW + q;

    int moff;
    if (sw > 0) { moff = base - 4; if (moff < 0) moff = 0; }
    else        { moff = base + 4; if (moff > PLANE - 4) moff = PLANE - 4; }

    float m0 = 1.f, m1 = 1.f, m2 = 1.f, m3 = 1.f;
    if (q == 0)      { if (sw >= 1) m0 = 0.f; if (sw == 2) m1 = 0.f; }
    if (q == WW - 4) { if (sw <= -1) m3 = 0.f; if (sw == -2) m2 = 0.f; }

    const int c0 = g * CG + csub * 16;
    const float* __restrict__ pb = x   + ((size_t)b * CHAN + c0) * PLANE;
    float*       __restrict__ ob = out + ((size_t)b * CHAN + c0) * PLANE;
    const float4 wv = *(const float4*)(g_w0 + (size_t)b * PLANE + base);

    switch (sw) {
        case  0: sb_loop< 0>(pb, ob, base, moff, hoff, hm, m0, m1, m2, m3, wv); break;
        case  1: sb_loop< 1>(pb, ob, base, moff, hoff, hm, m0, m1, m2, m3, wv); break;
        case  2: sb_loop< 2>(pb, ob, base, moff, hoff, hm, m0, m1, m2, m3, wv); break;
        case -1: sb_loop<-1>(pb, ob, base, moff, hoff, hm, m0, m1, m2, m3, wv); break;
        default: sb_loop<-2>(pb, ob, base, moff, hoff, hm, m0, m1, m2, m3, wv); break;
    }
}

// ===========================================================================
// DIAGNOSTIC KERNELS (write only to d_ws; durations read from rocprof top-5).
// Each does 4 passes with a memory-clobber between passes (no DCE), so its
// duration exceeds the ~50us top-5 cutoff. Removed next round.
// ===========================================================================
#define NTOT ((size_t)BATCH * CHAN * PLANE)   // 20.97M floats

// D1: canonical grid-stride float4 copy x->ws, 4 passes (672 MB traffic)
__global__ __launch_bounds__(256) void k_diag_copy_canon(
        const float* __restrict__ x, float* __restrict__ ws)
{
    const size_t n4 = NTOT / 4;
    const size_t stride = (size_t)gridDim.x * 256;
    for (int pass = 0; pass < 4; ++pass) {
        for (size_t i = blockIdx.x * 256 + threadIdx.x; i < n4; i += stride)
            ((float4*)ws)[i] = ((const float4*)x)[i];
        asm volatile("" ::: "memory");
    }
}

// D4: k3-shaped copy (1280 blocks, 16-channel loop, 1 load + 1 store/iter)
__global__ __launch_bounds__(256) void k_diag_copy_k3shape(
        const float* __restrict__ x, float* __restrict__ ws)
{
    const int tid  = threadIdx.x;
    const int lane = tid & 63;
    const int csub = tid >> 6;
    const int bid  = blockIdx.x;
    const int s    = bid & 15;
    const int g    = (bid >> 4) % NGRP;
    const int b    = bid / (NGRP * 16);
    const int base = s * 256 + lane * 4;     // float index within plane
    const int c0   = g * CG + csub * 16;

    const float* __restrict__ pb = x  + ((size_t)b * CHAN + c0) * PLANE;
    float*       __restrict__ ob = ws + ((size_t)b * CHAN + c0) * PLANE;

    for (int pass = 0; pass < 4; ++pass) {
        const float* p = pb; float* o = ob;
#pragma unroll
        for (int i = 0; i < 16; ++i) {
            *(float4*)(o + base) = *(const float4*)(p + base);
            p += PLANE; o += PLANE;
        }
        asm volatile("" ::: "memory");
    }
}

// D2: k3's exact 3-load pattern, no in-loop stores (reads only)
__global__ __launch_bounds__(256) void k_diag_load3(
        const float* __restrict__ x,
        const int* __restrict__ sh_arr, const int* __restrict__ sw_arr,
        float* __restrict__ ws)
{
    const int tid  = threadIdx.x;
    const int lane = tid & 63;
    const int csub = tid >> 6;
    const int bid  = blockIdx.x;
    const int s    = bid & 15;
    const int g    = (bid >> 4) % NGRP;
    const int b    = bid / (NGRP * 16);
    const int sh   = sh_arr[g];
    const int sw   = sw_arr[g];

    const int p4   = s * 64 + lane;
    const int r    = p4 >> 4;
    const int q    = (p4 & 15) * 4;
    const int base = r * WW + q;
    const int rs   = r - sh;
    const int rsc  = rs < 0 ? 0 : (rs > HH - 1 ? HH - 1 : rs);
    const int hoff = rsc * WW + q;
    int moff;
    if (sw > 0) { moff = base - 4; if (moff < 0) moff = 0; }
    else        { moff = base + 4; if (moff > PLANE - 4) moff = PLANE - 4; }

    const int c0 = g * CG + csub * 16;
    const float* __restrict__ pb = x + ((size_t)b * CHAN + c0) * PLANE;

    float4 acc = make_float4(0.f, 0.f, 0.f, 0.f);
    for (int pass = 0; pass < 4; ++pass) {
        const float* p = pb;
#pragma unroll
        for (int i = 0; i < 16; ++i) {
            const float4 a = *(const float4*)(p + base);
            const float4 m = *(const float4*)(p + moff);
            const float4 h = *(const float4*)(p + hoff);
            acc.x += a.x + m.x + h.x;
            acc.y += a.y + m.y + h.y;
            acc.z += a.z + m.z + h.z;
            acc.w += a.w + m.w + h.w;
            p += PLANE;
        }
        asm volatile("" ::: "memory");
    }
    // one tiny store per thread keeps everything live (5 MB total)
    *(float4*)(ws + ((size_t)bid * 256 + tid) * 4) = acc;
}

// D3: k3's store pattern only (writes only), 4 passes
__global__ __launch_bounds__(256) void k_diag_store16(
        float* __restrict__ ws)
{
    const int tid  = threadIdx.x;
    const int lane = tid & 63;
    const int csub = tid >> 6;
    const int bid  = blockIdx.x;
    const int s    = bid & 15;
    const int g    = (bid >> 4) % NGRP;
    const int b    = bid / (NGRP * 16);
    const int base = s * 256 + lane * 4;
    const int c0   = g * CG + csub * 16;

    float* __restrict__ ob = ws + ((size_t)b * CHAN + c0) * PLANE;
    const float4 v = *(const float4*)(g_w0 + (size_t)b * PLANE + base);

    for (int pass = 0; pass < 4; ++pass) {
        float* o = ob;
#pragma unroll
        for (int i = 0; i < 16; ++i) {
            *(float4*)(o + base) = v;
            o += PLANE;
        }
        asm volatile("" ::: "memory");
    }
}

extern "C" void kernel_launch(void* const* d_in, const int* in_sizes, int n_in,
                              void* d_out, int out_size, void* d_ws, size_t ws_size,
                              hipStream_t stream)
{
    const float* x   = (const float*)d_in[0];
    const float* eg  = (const float*)d_in[1];
    const float* w1  = (const float*)d_in[2];
    const float* b1  = (const float*)d_in[3];
    const float* w2  = (const float*)d_in[4];
    const float* b2  = (const float*)d_in[5];
    const int*   shh = (const int*)d_in[6];
    const int*   shw = (const int*)d_in[7];
    float* out = (float*)d_out;

    // production pipeline (correctness)
    k_reduce_mean<<<BATCH * HH, 256, 0, stream>>>(eg);
    k_conv_dir<<<BATCH * 16, 256, 0, stream>>>(w1, b1, w2, b2);
    k_shift_blend<<<BATCH * NGRP * 16, 256, 0, stream>>>(x, shh, shw, out);

    // diagnostics (one round only; write to d_ws, never to d_out)
    if (ws_size >= (size_t)96 * 1024 * 1024) {
        float* ws = (float*)d_ws;
        k_diag_copy_canon  <<<2048, 256, 0, stream>>>(x, ws);
        k_diag_copy_k3shape<<<BATCH * NGRP * 16, 256, 0, stream>>>(x, ws);
        k_diag_load3       <<<BATCH * NGRP * 16, 256, 0, stream>>>(x, shh, shw, ws);
        k_diag_store16     <<<BATCH * NGRP * 16, 256, 0, stream>>>(ws);
    }
}

// Round 12
// 88.686 us; speedup vs baseline: 3.5757x; 3.5757x over previous
//
#include <hip/hip_runtime.h>

// Problem constants (from setup_inputs): B=16, C=320, H=W=64, G=5, Cg=64
#define BATCH 16
#define CHAN  320
#define HH    64
#define WW    64
#define PLANE (HH*WW)            // 4096
#define NGRP  5
#define CG    64                 // CHAN / NGRP
#define NTOT  ((size_t)BATCH * CHAN * PLANE)   // 20.97M floats
#define N4    (NTOT / 4)                       // 5,242,880 float4
#define GSBLK 2048
#define GSSTRIDE (GSBLK * 256)                 // 524288 -> exactly 10 iters

// Static device scratch (module-load allocated). Fully overwritten before
// being read on every kernel_launch call.
__device__ float g_em[BATCH * PLANE];   // channel SUM of edge_guidance
__device__ float g_w0[BATCH * PLANE];   // softmax weight for the H-shift term

// ---------------------------------------------------------------------------
// Kernel 1: g_em[b,r,q] = sum_c edge_guidance[b,c,r,q]
// ---------------------------------------------------------------------------
__global__ void k_reduce_mean(const float* __restrict__ eg)
{
    __shared__ float red[256];
    const int bid = blockIdx.x;           // b*64 + r
    const int b = bid >> 6;
    const int r = bid & 63;
    const int q   = threadIdx.x & 63;
    const int grp = threadIdx.x >> 6;     // 0..3, each owns 80 channels

    const float* p = eg + (((size_t)b * CHAN + (size_t)grp * 80) * PLANE) + r * WW + q;
    float s = 0.f;
#pragma unroll 8
    for (int c = 0; c < 80; ++c)
        s += p[(size_t)c * PLANE];

    red[threadIdx.x] = s;
    __syncthreads();
    if (grp == 0) {
        g_em[(size_t)bid * 64 + q] = red[q] + red[q + 64] + red[q + 128] + red[q + 192];
    }
}

// ---------------------------------------------------------------------------
// Kernel 2: fused conv1+relu -> conv2 -> softmax -> w0
// ---------------------------------------------------------------------------
__global__ void k_conv_dir(const float* __restrict__ w1, const float* __restrict__ b1,
                           const float* __restrict__ w2, const float* __restrict__ b2)
{
    __shared__ float sem[20][20];
    __shared__ float shh[18][18];
    __shared__ float sw1[16][9];
    __shared__ float sb1[16];
    __shared__ float sw2[2][16][9];
    __shared__ float sb2[2];

    const int bid = blockIdx.x;
    const int b  = bid >> 4;
    const int t  = bid & 15;
    const int r0 = (t >> 2) * 16;
    const int q0 = (t & 3) * 16;
    const int tid = threadIdx.x;

    if (tid < 144) sw1[tid / 9][tid % 9] = w1[tid];
    if (tid < 16)  sb1[tid] = b1[tid];
    for (int i = tid; i < 288; i += 256) ((float*)sw2)[i] = w2[i];
    if (tid < 2)   sb2[tid] = b2[tid];

    const float scale = 1.0f / (float)CHAN;
    for (int i = tid; i < 400; i += 256) {
        const int lr = i / 20, lq = i % 20;
        const int r = r0 + lr - 2, q = q0 + lq - 2;
        float v = 0.f;
        if ((unsigned)r < HH && (unsigned)q < WW)
            v = g_em[((size_t)b * HH + r) * WW + q] * scale;
        sem[lr][lq] = v;
    }
    __syncthreads();

    const int lr = tid >> 4;
    const int lq = tid & 15;
    float l0 = sb2[0];
    float l1 = sb2[1];

    for (int i = 0; i < 16; ++i) {
        for (int p = tid; p < 324; p += 256) {
            const int hr = p / 18, hq = p % 18;
            const int gr = r0 - 1 + hr, gq = q0 - 1 + hq;
            float acc = 0.f;
            if ((unsigned)gr < HH && (unsigned)gq < WW) {
                acc = sb1[i];
#pragma unroll
                for (int dr = 0; dr < 3; ++dr)
#pragma unroll
                    for (int dq = 0; dq < 3; ++dq)
                        acc += sem[hr + dr][hq + dq] * sw1[i][dr * 3 + dq];
                acc = fmaxf(acc, 0.f);
            }
            shh[hr][hq] = acc;
        }
        __syncthreads();
#pragma unroll
        for (int dr = 0; dr < 3; ++dr)
#pragma unroll
            for (int dq = 0; dq < 3; ++dq) {
                const float hv = shh[lr + dr][lq + dq];
                l0 += hv * sw2[0][i][dr * 3 + dq];
                l1 += hv * sw2[1][i][dr * 3 + dq];
            }
        __syncthreads();
    }

    const float m  = fmaxf(l0, l1);
    const float e0 = expf(l0 - m);
    const float e1 = expf(l1 - m);
    const float w0v = e0 / (e0 + e1);
    g_w0[((size_t)b * HH + (r0 + lr)) * WW + (q0 + lq)] = w0v;
}

// ---------------------------------------------------------------------------
// Diagnostic reference (kept ONE round): D1-clone copy x -> out, launched
// BEFORE k_shift_blend_gs which then overwrites out with the correct result.
// Times "pure copy into d_out in the production slot" (~26us expected).
// ---------------------------------------------------------------------------
__global__ __launch_bounds__(256) void k_diag_copy_out(
        const float* __restrict__ x, float* __restrict__ o)
{
    const size_t st = (size_t)gridDim.x * 256;
    for (size_t i = (size_t)blockIdx.x * 256 + threadIdx.x; i < N4; i += st)
        ((float4*)o)[i] = ((const float4*)x)[i];
}

// ---------------------------------------------------------------------------
// Kernel 3 v8: grid-stride D1-clone with fused blend; forced MLP.
// 2048 blocks x 256 thr; 10 float4/thread in 2 chunks of 5. Phase A issues
// all 20 loads of a chunk into registers; asm "memory" barrier pins them
// before phase B's stores (the scheduler serialized every previous variant
// to VGPR=36; this structure makes that impossible). Shifts are packed into
// 2 ints (3b each); per-lane branch-free selects; bounds via masks.
// A wave's 64 consecutive float4s never cross a plane (64 | 1024), so all
// its lanes share one (b,c,g) -> loads stay coalesced like D1.
// ---------------------------------------------------------------------------
__global__ __launch_bounds__(256, 1) void k_shift_blend_gs(
        const float* __restrict__ x,
        const int* __restrict__ sh_arr, const int* __restrict__ sw_arr,
        float* __restrict__ out)
{
    const int gtid = blockIdx.x * 256 + threadIdx.x;

    int pack_h = 0, pack_w = 0;
#pragma unroll
    for (int k = 0; k < NGRP; ++k) {
        pack_h |= (sh_arr[k] + 2) << (3 * k);
        pack_w |= (sw_arr[k] + 2) << (3 * k);
    }

#pragma unroll
    for (int half = 0; half < 2; ++half) {
        float4 av[5], mv[5], hv[5], wv[5];
        int   fi[5], swv[5], qfv[5];
        float hmv[5];

#pragma unroll
        for (int u = 0; u < 5; ++u) {
            const int i4 = gtid + (half * 5 + u) * GSSTRIDE;
            const int p4 = i4 & 1023;          // float4 idx within plane
            const int pl = i4 >> 10;           // plane = b*CHAN + c
            const int b  = pl / CHAN;
            const int c  = pl - b * CHAN;
            const int g  = c >> 6;
            const int r  = p4 >> 4;
            const int qf = (p4 & 15) << 2;
            const int f  = i4 << 2;            // global float index (fits int)
            const int ps = pl << 12;           // plane start (floats)

            const int sh = ((pack_h >> (3 * g)) & 7) - 2;
            const int sw = ((pack_w >> (3 * g)) & 7) - 2;

            const int rs  = r - sh;
            hmv[u] = ((unsigned)rs < HH) ? 1.f : 0.f;
            const int rsc = rs < 0 ? 0 : (rs > HH - 1 ? HH - 1 : rs);

            // aligned neighbor float4, clamped in-plane (clamped lanes are
            // fully masked in phase B)
            const int mlo = (f - 4 < ps) ? ps : f - 4;
            const int mhi = (f + 4 > ps + PLANE - 4) ? ps + PLANE - 4 : f + 4;
            const int mo  = (sw > 0) ? mlo : mhi;

            fi[u] = f; swv[u] = sw; qfv[u] = qf;
            av[u] = *(const float4*)(x + f);
            mv[u] = *(const float4*)(x + mo);
            hv[u] = *(const float4*)(x + ps + rsc * WW + qf);
            wv[u] = *(const float4*)(g_w0 + (b << 12) + p4 * 4);
        }

        asm volatile("" ::: "memory");   // loads pinned above, stores below

#pragma unroll
        for (int u = 0; u < 5; ++u) {
            const int sw = swv[u], qf = qfv[u];
            const float4 v = av[u], m = mv[u];

            // W-shift component select (xw[k] = X[r, qf+k-sw], m = neighbor)
            float xw0 = sw == 2 ? m.z : sw == 1 ? m.w : sw == 0 ? v.x : sw == -1 ? v.y : v.z;
            float xw1 = sw == 2 ? m.w : sw == 1 ? v.x : sw == 0 ? v.y : sw == -1 ? v.z : v.w;
            float xw2 = sw == 2 ? v.x : sw == 1 ? v.y : sw == 0 ? v.z : sw == -1 ? v.w : m.x;
            float xw3 = sw == 2 ? v.y : sw == 1 ? v.z : sw == 0 ? v.w : sw == -1 ? m.x : m.y;
            // zero-pad out-of-image columns
            xw0 = ((unsigned)(qf + 0 - sw) < WW) ? xw0 : 0.f;
            xw1 = ((unsigned)(qf + 1 - sw) < WW) ? xw1 : 0.f;
            xw2 = ((unsigned)(qf + 2 - sw) < WW) ? xw2 : 0.f;
            xw3 = ((unsigned)(qf + 3 - sw) < WW) ? xw3 : 0.f;

            const float hm = hmv[u];
            const float4 w = wv[u], h = hv[u];
            float4 o;
            o.x = xw0 + w.x * (hm * h.x - xw0);
            o.y = xw1 + w.y * (hm * h.y - xw1);
            o.z = xw2 + w.z * (hm * h.z - xw2);
            o.w = xw3 + w.w * (hm * h.w - xw3);
            *(float4*)(out + fi[u]) = o;
        }
    }
}

extern "C" void kernel_launch(void* const* d_in, const int* in_sizes, int n_in,
                              void* d_out, int out_size, void* d_ws, size_t ws_size,
                              hipStream_t stream)
{
    const float* x   = (const float*)d_in[0];
    const float* eg  = (const float*)d_in[1];
    const float* w1  = (const float*)d_in[2];
    const float* b1  = (const float*)d_in[3];
    const float* w2  = (const float*)d_in[4];
    const float* b2  = (const float*)d_in[5];
    const int*   shh = (const int*)d_in[6];
    const int*   shw = (const int*)d_in[7];
    float* out = (float*)d_out;

    k_reduce_mean<<<BATCH * HH, 256, 0, stream>>>(eg);
    k_conv_dir<<<BATCH * 16, 256, 0, stream>>>(w1, b1, w2, b2);
    // in-situ reference: pure copy into d_out (overwritten by k3 below)
    k_diag_copy_out<<<GSBLK, 256, 0, stream>>>(x, out);
    k_shift_blend_gs<<<GSBLK, 256, 0, stream>>>(x, shh, shw, out);
}